// Round 7
// baseline (8818.318 us; speedup 1.0000x reference)
//
#include <hip/hip_runtime.h>

// Packed-LSTM (B=64, S=2048, H=512, V=25) + final linear head.
// Two-group interleave per WG: 32 WGs x 256 thr. Set s = bid&1 owns sorted
// ranks [32s, 32s+32); within the set, group A = even local ranks, group B
// = odd local ranks (interleaved pairing -> T_A ~ T_B, tiny tail). Each WG
// owns 32 hidden units (128 gate rows) of BOTH groups; W_hh slice (bf16
// MFMA B-frags, 128 VGPRs) and xgt are SHARED between groups.
//
// Round t: [check A -> MFMA A -> issue B-poll -> cell A -> store A]
//          [check B -> MFMA B -> issue A-poll(t+1) -> cell B -> store B]
// Cross-WG h exchange: round-2's self-tagged relaxed qwords through LLC,
// wave-coalesced (qidx = producerWG*256 + batch*16 + unitpair, qword =
// (step_tag<<32)|2xbf16). The poll loads for each group are ISSUED under
// the other group's compute and CHECKED one phase later, hiding the
// store->visible latency; on a stale check the round-2 spin loop re-polls
// (correctness fallback). Parity double buffer; 2-deep pipeline bound
// prevents overwrite races (a producer reaches its t+2 store only after
// observing all t+1 tags, implying every consumer consumed t).

#define VOCAB 25
#define HIDDEN 512
#define BATCH 64
#define SEQ 2048
#define GB 16    // batches per group
#define NG 4     // logical groups (2 sets x 2)
#define WPG 16   // workgroups per group/set
#define HSL 32   // hidden units per WG
#define RWG 128  // gate rows per WG = 4*HSL
#define NTHREADS 256
#define HGQ (GB * HIDDEN / 2)  // 4096 tagged qwords per group parity buffer

typedef short s16x8 __attribute__((ext_vector_type(8)));
typedef float f32x4 __attribute__((ext_vector_type(4)));
typedef unsigned long long ull;

__device__ inline unsigned short f2bf(float x) {
  unsigned u = __float_as_uint(x);
  u += 0x7fffu + ((u >> 16) & 1u);  // RNE
  return (unsigned short)(u >> 16);
}
__device__ inline float sigf(float x) { return 1.0f / (1.0f + __expf(-x)); }
__device__ inline float tanh_fast(float x) { return 2.0f / (1.0f + __expf(-2.0f * x)) - 1.0f; }

__global__ void prep_kernel(ull* hg, float* out) {
  const int i = blockIdx.x * blockDim.x + threadIdx.x;
  const int n = blockDim.x * gridDim.x;
  for (int k = i; k < 2 * NG * HGQ; k += n) hg[k] = 0ull;  // tag=0: never matches t>=1
  if (i < BATCH) out[i] = 0.f;
}

__global__ __launch_bounds__(NTHREADS, 1) void lstm_persistent(
    const int* __restrict__ tokens, const int* __restrict__ lengths,
    const float* __restrict__ W_ih, const float* __restrict__ W_hh,
    const float* __restrict__ b_ih, const float* __restrict__ b_hh,
    const float* __restrict__ fc_w, const float* __restrict__ fc_b,
    float* __restrict__ out, ull* hg) {
  const int tid = threadIdx.x;
  const int bid = blockIdx.x;
  const int s = bid & 1;   // set 0/1
  const int w = bid >> 1;  // wg-in-set 0..15
  const int gidA = 2 * s, gidB = 2 * s + 1;

  __shared__ __align__(16) unsigned short hbufA[GB][HIDDEN + 8];
  __shared__ __align__(16) unsigned short hbufB[GB][HIDDEN + 8];
  __shared__ float gatesbA[GB][RWG + 5];
  __shared__ float gatesbB[GB][RWG + 5];
  __shared__ float xgt[VOCAB][RWG + 5];  // shared: same weights for both groups
  __shared__ int lenAll[BATCH];
  __shared__ int order_[BATCH];
  __shared__ int gIdxA[GB], gLenA[GB], gIdxB[GB], gLenB[GB];

  if (tid < BATCH) lenAll[tid] = lengths[tid];
  __syncthreads();
  if (tid < BATCH) {  // stable argsort(-lengths): rank by count
    const int L = lenAll[tid];
    int r = 0;
    for (int j = 0; j < BATCH; ++j) {
      const int lj = lenAll[j];
      r += ((lj > L) || (lj == L && j < tid)) ? 1 : 0;
    }
    order_[r] = tid;
  }
  __syncthreads();
  if (tid < GB) {  // interleaved pairing: A = even local rank, B = odd
    const int ra = s * 32 + 2 * tid;
    const int oa = order_[ra], ob = order_[ra + 1];
    gIdxA[tid] = oa; gLenA[tid] = lenAll[oa];
    gIdxB[tid] = ob; gLenB[tid] = lenAll[ob];
  }
  for (int i = tid; i < GB * (HIDDEN + 8); i += NTHREADS) {
    ((unsigned short*)hbufA)[i] = 0;  // h0 = 0
    ((unsigned short*)hbufB)[i] = 0;
  }
  for (int i = tid; i < VOCAB * RWG; i += NTHREADS) {
    const int v = i / RWG, rl = i % RWG;
    const int rg = (rl >> 5) * HIDDEN + w * HSL + (rl & 31);
    xgt[v][rl] = W_ih[rg * VOCAB + v] + b_ih[rg] + b_hh[rg];
  }
  __syncthreads();

  const int TA = gLenA[0];  // set maxlen (A has the longer of each pair)
  const int TB = gLenB[0];
  const int lane = tid & 63;
  const int wv = tid >> 6;
  const int m16 = lane & 15;
  const int quad = lane >> 4;

  // B fragments (bf16 W_hh slice) in VGPRs: wave wv owns ntiles {wv, wv+4}.
  s16x8 Bf[2][16];
#pragma unroll
  for (int nti = 0; nti < 2; ++nti) {
    const int nt = wv + 4 * nti;
    const int rl = nt * 16 + m16;  // local gate-row 0..127
    const int rg = (rl >> 5) * HIDDEN + w * HSL + (rl & 31);
    const float* wr = W_hh + (size_t)rg * HIDDEN;
#pragma unroll
    for (int kt = 0; kt < 16; ++kt) {
      const float* p = wr + kt * 32 + quad * 8;
#pragma unroll
      for (int e = 0; e < 8; ++e) Bf[nti][kt][e] = (short)f2bf(p[e]);
    }
  }

  // Cell state: thread (cb,cs) owns hidden units jj0,jj1 of batch cb (per group).
  const int cb = tid >> 4;
  const int cs = tid & 15;
  const int jj0 = 2 * cs, jj1 = 2 * cs + 1;
  const int myLenA = gLenA[cb], myLenB = gLenB[cb];
  const int* tokRowA = tokens + (size_t)gIdxA[cb] * SEQ;
  const int* tokRowB = tokens + (size_t)gIdxB[cb] * SEQ;
  ull* const bA0 = hg + (size_t)gidA * HGQ;
  ull* const bA1 = hg + (size_t)(NG + gidA) * HGQ;
  ull* const bB0 = hg + (size_t)gidB * HGQ;
  ull* const bB1 = hg + (size_t)(NG + gidB) * HGQ;

  ull qA[16], qB[16];  // prefetched tagged words
  float cA0 = 0.f, cA1 = 0.f, hA0 = 0.f, hA1 = 0.f;
  float cB0 = 0.f, cB1 = 0.f, hB0 = 0.f, hB1 = 0.f;

  for (int t = 0; t < TA; ++t) {
    // ================= phase A =================
    const int tokA = tokRowA[t];
    if (t > 0) {
      bool ok = true;
#pragma unroll
      for (int r = 0; r < 16; ++r) ok &= ((unsigned)(qA[r] >> 32) == (unsigned)t);
      if (!ok) {  // stale prefetch -> spin re-poll (round-2 loop)
        const ull* src = ((t & 1) ? bA1 : bA0) + tid;
        for (;;) {
          ok = true;
#pragma unroll
          for (int r = 0; r < 16; ++r)
            qA[r] = __hip_atomic_load(src + r * 256, __ATOMIC_RELAXED,
                                      __HIP_MEMORY_SCOPE_AGENT);
#pragma unroll
          for (int r = 0; r < 16; ++r) ok &= ((unsigned)(qA[r] >> 32) == (unsigned)t);
          if (ok) break;
        }
      }
#pragma unroll
      for (int r = 0; r < 16; ++r)
        *(unsigned*)&hbufA[cb][r * 32 + jj0] = (unsigned)qA[r];
    }
    __syncthreads();  // hbufA staged
    {
      f32x4 acc0a = {0.f, 0.f, 0.f, 0.f}, acc0b = {0.f, 0.f, 0.f, 0.f};
      f32x4 acc1a = {0.f, 0.f, 0.f, 0.f}, acc1b = {0.f, 0.f, 0.f, 0.f};
#pragma unroll
      for (int kt = 0; kt < 16; kt += 2) {
        const s16x8 A0 = *(const s16x8*)&hbufA[m16][kt * 32 + quad * 8];
        const s16x8 A1 = *(const s16x8*)&hbufA[m16][(kt + 1) * 32 + quad * 8];
        acc0a = __builtin_amdgcn_mfma_f32_16x16x32_bf16(A0, Bf[0][kt], acc0a, 0, 0, 0);
        acc1a = __builtin_amdgcn_mfma_f32_16x16x32_bf16(A0, Bf[1][kt], acc1a, 0, 0, 0);
        acc0b = __builtin_amdgcn_mfma_f32_16x16x32_bf16(A1, Bf[0][kt + 1], acc0b, 0, 0, 0);
        acc1b = __builtin_amdgcn_mfma_f32_16x16x32_bf16(A1, Bf[1][kt + 1], acc1b, 0, 0, 0);
      }
      const f32x4 acc0 = acc0a + acc0b;
      const f32x4 acc1 = acc1a + acc1b;
#pragma unroll
      for (int v = 0; v < 4; ++v) {
        gatesbA[quad * 4 + v][wv * 16 + m16] = acc0[v];
        gatesbA[quad * 4 + v][(wv + 4) * 16 + m16] = acc1[v];
      }
    }
    __syncthreads();  // gatesA ready
    // issue B's poll loads (step t) under A's cell phase
    if (t > 0 && t < TB) {
      const ull* src = ((t & 1) ? bB1 : bB0) + tid;
#pragma unroll
      for (int r = 0; r < 16; ++r)
        qB[r] = __hip_atomic_load(src + r * 256, __ATOMIC_RELAXED,
                                  __HIP_MEMORY_SCOPE_AGENT);
    }
    {  // cell A + publish
      const float pi0 = gatesbA[cb][jj0] + xgt[tokA][jj0];
      const float pf0 = gatesbA[cb][32 + jj0] + xgt[tokA][32 + jj0];
      const float pg0 = gatesbA[cb][64 + jj0] + xgt[tokA][64 + jj0];
      const float po0 = gatesbA[cb][96 + jj0] + xgt[tokA][96 + jj0];
      const float pi1 = gatesbA[cb][jj1] + xgt[tokA][jj1];
      const float pf1 = gatesbA[cb][32 + jj1] + xgt[tokA][32 + jj1];
      const float pg1 = gatesbA[cb][64 + jj1] + xgt[tokA][64 + jj1];
      const float po1 = gatesbA[cb][96 + jj1] + xgt[tokA][96 + jj1];
      if (t < myLenA) {
        const float i0 = sigf(pi0), f0 = sigf(pf0), g0 = tanh_fast(pg0), o0 = sigf(po0);
        cA0 = f0 * cA0 + i0 * g0;
        hA0 = o0 * tanh_fast(cA0);
        const float i1 = sigf(pi1), f1 = sigf(pf1), g1 = tanh_fast(pg1), o1 = sigf(po1);
        cA1 = f1 * cA1 + i1 * g1;
        hA1 = o1 * tanh_fast(cA1);
      }
      if (t + 1 < TA) {
        const unsigned payload = (unsigned)f2bf(hA0) | ((unsigned)f2bf(hA1) << 16);
        const ull qv = ((ull)(unsigned)(t + 1) << 32) | payload;
        ull* hp = (((t + 1) & 1) ? bA1 : bA0) + w * 256 + tid;
        __hip_atomic_store(hp, qv, __ATOMIC_RELAXED, __HIP_MEMORY_SCOPE_AGENT);
      }
    }

    // ================= phase B =================
    if (t < TB) {
      const int tokB = tokRowB[t];
      if (t > 0) {
        bool ok = true;
#pragma unroll
        for (int r = 0; r < 16; ++r) ok &= ((unsigned)(qB[r] >> 32) == (unsigned)t);
        if (!ok) {
          const ull* src = ((t & 1) ? bB1 : bB0) + tid;
          for (;;) {
            ok = true;
#pragma unroll
            for (int r = 0; r < 16; ++r)
              qB[r] = __hip_atomic_load(src + r * 256, __ATOMIC_RELAXED,
                                        __HIP_MEMORY_SCOPE_AGENT);
#pragma unroll
            for (int r = 0; r < 16; ++r) ok &= ((unsigned)(qB[r] >> 32) == (unsigned)t);
            if (ok) break;
          }
        }
#pragma unroll
        for (int r = 0; r < 16; ++r)
          *(unsigned*)&hbufB[cb][r * 32 + jj0] = (unsigned)qB[r];
      }
      __syncthreads();  // hbufB staged
      {
        f32x4 acc0a = {0.f, 0.f, 0.f, 0.f}, acc0b = {0.f, 0.f, 0.f, 0.f};
        f32x4 acc1a = {0.f, 0.f, 0.f, 0.f}, acc1b = {0.f, 0.f, 0.f, 0.f};
#pragma unroll
        for (int kt = 0; kt < 16; kt += 2) {
          const s16x8 A0 = *(const s16x8*)&hbufB[m16][kt * 32 + quad * 8];
          const s16x8 A1 = *(const s16x8*)&hbufB[m16][(kt + 1) * 32 + quad * 8];
          acc0a = __builtin_amdgcn_mfma_f32_16x16x32_bf16(A0, Bf[0][kt], acc0a, 0, 0, 0);
          acc1a = __builtin_amdgcn_mfma_f32_16x16x32_bf16(A0, Bf[1][kt], acc1a, 0, 0, 0);
          acc0b = __builtin_amdgcn_mfma_f32_16x16x32_bf16(A1, Bf[0][kt + 1], acc0b, 0, 0, 0);
          acc1b = __builtin_amdgcn_mfma_f32_16x16x32_bf16(A1, Bf[1][kt + 1], acc1b, 0, 0, 0);
        }
        const f32x4 acc0 = acc0a + acc0b;
        const f32x4 acc1 = acc1a + acc1b;
#pragma unroll
        for (int v = 0; v < 4; ++v) {
          gatesbB[quad * 4 + v][wv * 16 + m16] = acc0[v];
          gatesbB[quad * 4 + v][(wv + 4) * 16 + m16] = acc1[v];
        }
      }
      __syncthreads();  // gatesB ready
      // issue A's poll loads (step t+1) under B's cell phase
      if (t + 1 < TA) {
        const ull* src = (((t + 1) & 1) ? bA1 : bA0) + tid;
#pragma unroll
        for (int r = 0; r < 16; ++r)
          qA[r] = __hip_atomic_load(src + r * 256, __ATOMIC_RELAXED,
                                    __HIP_MEMORY_SCOPE_AGENT);
      }
      {  // cell B + publish
        const float pi0 = gatesbB[cb][jj0] + xgt[tokB][jj0];
        const float pf0 = gatesbB[cb][32 + jj0] + xgt[tokB][32 + jj0];
        const float pg0 = gatesbB[cb][64 + jj0] + xgt[tokB][64 + jj0];
        const float po0 = gatesbB[cb][96 + jj0] + xgt[tokB][96 + jj0];
        const float pi1 = gatesbB[cb][jj1] + xgt[tokB][jj1];
        const float pf1 = gatesbB[cb][32 + jj1] + xgt[tokB][32 + jj1];
        const float pg1 = gatesbB[cb][64 + jj1] + xgt[tokB][64 + jj1];
        const float po1 = gatesbB[cb][96 + jj1] + xgt[tokB][96 + jj1];
        if (t < myLenB) {
          const float i0 = sigf(pi0), f0 = sigf(pf0), g0 = tanh_fast(pg0), o0 = sigf(po0);
          cB0 = f0 * cB0 + i0 * g0;
          hB0 = o0 * tanh_fast(cB0);
          const float i1 = sigf(pi1), f1 = sigf(pf1), g1 = tanh_fast(pg1), o1 = sigf(po1);
          cB1 = f1 * cB1 + i1 * g1;
          hB1 = o1 * tanh_fast(cB1);
        }
        if (t + 1 < TB) {
          const unsigned payload = (unsigned)f2bf(hB0) | ((unsigned)f2bf(hB1) << 16);
          const ull qv = ((ull)(unsigned)(t + 1) << 32) | payload;
          ull* hp = (((t + 1) & 1) ? bB1 : bB0) + w * 256 + tid;
          __hip_atomic_store(hp, qv, __ATOMIC_RELAXED, __HIP_MEMORY_SCOPE_AGENT);
        }
      }
    } else {
      // B finished: still issue A's next-step polls (tail reverts to spin mode)
      if (t + 1 < TA) {
        const ull* src = (((t + 1) & 1) ? bA1 : bA0) + tid;
#pragma unroll
        for (int r = 0; r < 16; ++r)
          qA[r] = __hip_atomic_load(src + r * 256, __ATOMIC_RELAXED,
                                    __HIP_MEMORY_SCOPE_AGENT);
      }
    }
  }

  // out[rank] = h . fc_w + fc_b; rank A = s*32+2cb, rank B = s*32+2cb+1
  {
    float part = hA0 * fc_w[w * HSL + jj0] + hA1 * fc_w[w * HSL + jj1];
    part += __shfl_down(part, 8, 16);
    part += __shfl_down(part, 4, 16);
    part += __shfl_down(part, 2, 16);
    part += __shfl_down(part, 1, 16);
    if (cs == 0) {
      if (w == 0) part += fc_b[0];
      atomicAdd(&out[s * 32 + 2 * cb], part);
    }
  }
  {
    float part = hB0 * fc_w[w * HSL + jj0] + hB1 * fc_w[w * HSL + jj1];
    part += __shfl_down(part, 8, 16);
    part += __shfl_down(part, 4, 16);
    part += __shfl_down(part, 2, 16);
    part += __shfl_down(part, 1, 16);
    if (cs == 0) {
      if (w == 0) part += fc_b[0];
      atomicAdd(&out[s * 32 + 2 * cb + 1], part);
    }
  }
}

extern "C" void kernel_launch(void* const* d_in, const int* in_sizes, int n_in,
                              void* d_out, int out_size, void* d_ws, size_t ws_size,
                              hipStream_t stream) {
  (void)in_sizes; (void)n_in; (void)out_size; (void)ws_size;
  const int* tokens = (const int*)d_in[0];
  const int* lengths = (const int*)d_in[1];
  const float* W_ih = (const float*)d_in[2];
  const float* W_hh = (const float*)d_in[3];
  const float* b_ih = (const float*)d_in[4];
  const float* b_hh = (const float*)d_in[5];
  const float* fc_w = (const float*)d_in[6];
  const float* fc_b = (const float*)d_in[7];
  float* out = (float*)d_out;
  ull* hglob = (ull*)d_ws;  // 256 KB tagged h double-buffer

  prep_kernel<<<32, 256, 0, stream>>>(hglob, out);
  lstm_persistent<<<32, NTHREADS, 0, stream>>>(tokens, lengths, W_ih, W_hh, b_ih, b_hh,
                                               fc_w, fc_b, out, hglob);
}

// Round 8
// 6892.546 us; speedup vs baseline: 1.2794x; 1.2794x over previous
//
#include <hip/hip_runtime.h>

// Packed-LSTM (B=64, S=2048, H=512, V=25) + final linear head.
// STAGGERED DUAL-GROUP design: 64 WGs x 256 thr. Sorted ranks split into 4
// pairs of 16; pair p is served by 16 WGs; within the pair, group P = even
// local ranks (8 batches), Q = odd. Each WG owns 32 hidden units (128 gate
// rows) of BOTH groups; W_hh B-fragments (VGPR) and xgt are shared. Per
// round: phase P {check/stage P -> MFMA P -> prefetch Q -> cell+store P},
// phase Q {check/stage Q -> MFMA Q -> prefetch P(t+1) -> cell+store Q}.
// Each group's store->visible latency hides under the other group's phase.
//
// Exchange: 16-bit-tagged dwords through LLC. Producer thread (cb,j) stores
// dword = (tag<<16)|bf16(h) at w*256+cb*32+j (1 KB contiguous/WG). Consumer
// polls qwords (2 units) with inline-asm global_load_dwordx2 sc0 sc1 pinned
// at the issue point (compiler cannot sink it), consumed one phase later via
// s_waitcnt vmcnt(1) + sched_barrier(0). Tag mismatch -> round-2 spin loop
// (correctness never depends on the prefetch hitting). Parity double buffer;
// 2-deep pipeline bound prevents overwrite races (producer stores t+2 only
// after checking all t+1 tags => every consumer holds t).

#define VOCAB 25
#define HIDDEN 512
#define BATCH 64
#define SEQ 2048
#define GBH 8    // batches per group
#define WPG 16   // workgroups per group
#define HSL 32   // hidden units per WG
#define RWG 128  // gate rows per WG
#define NTHREADS 256
#define GQW 2048  // qwords per group-parity buffer (8 batches * 512 units / 2)

typedef short s16x8 __attribute__((ext_vector_type(8)));
typedef float f32x4 __attribute__((ext_vector_type(4)));
typedef unsigned long long ull;

__device__ inline unsigned short f2bf(float x) {
  unsigned u = __float_as_uint(x);
  u += 0x7fffu + ((u >> 16) & 1u);  // RNE
  return (unsigned short)(u >> 16);
}
__device__ inline float sigf(float x) { return 1.0f / (1.0f + __expf(-x)); }
__device__ inline float tanh_fast(float x) { return 2.0f / (1.0f + __expf(-2.0f * x)) - 1.0f; }

#define PREFETCH8(QARR, QB)                                                  \
  asm volatile(                                                              \
      "global_load_dwordx2 %[a0], %[v0], %[b] sc0 sc1\n\t"                   \
      "global_load_dwordx2 %[a1], %[v0], %[b] offset:1024 sc0 sc1\n\t"       \
      "global_load_dwordx2 %[a2], %[v0], %[b] offset:2048 sc0 sc1\n\t"       \
      "global_load_dwordx2 %[a3], %[v0], %[b] offset:3072 sc0 sc1\n\t"       \
      "global_load_dwordx2 %[a4], %[v1], %[b] sc0 sc1\n\t"                   \
      "global_load_dwordx2 %[a5], %[v1], %[b] offset:1024 sc0 sc1\n\t"       \
      "global_load_dwordx2 %[a6], %[v1], %[b] offset:2048 sc0 sc1\n\t"       \
      "global_load_dwordx2 %[a7], %[v1], %[b] offset:3072 sc0 sc1"           \
      : [a0] "=&v"(QARR[0]), [a1] "=&v"(QARR[1]), [a2] "=&v"(QARR[2]),       \
        [a3] "=&v"(QARR[3]), [a4] "=&v"(QARR[4]), [a5] "=&v"(QARR[5]),       \
        [a6] "=&v"(QARR[6]), [a7] "=&v"(QARR[7])                             \
      : [v0] "v"(vo0), [v1] "v"(vo1), [b] "s"(QB)                            \
      : "memory")

#define TAGOK8(QARR, TU, OK)                                                 \
  do {                                                                       \
    OK = true;                                                               \
    _Pragma("unroll") for (int r_ = 0; r_ < 8; ++r_) {                       \
      OK &= (((unsigned)(QARR[r_] >> 16) & 0xFFFFu) == (TU));                \
      OK &= (((unsigned)(QARR[r_] >> 48)) == (TU));                          \
    }                                                                        \
  } while (0)

__global__ void prep_kernel(ull* hg, float* out) {
  const int i = blockIdx.x * blockDim.x + threadIdx.x;
  const int n = blockDim.x * gridDim.x;
  for (int k = i; k < 16 * GQW; k += n) hg[k] = 0ull;  // tag 0 never matches t>=1
  if (i < BATCH) out[i] = 0.f;
}

__global__ __launch_bounds__(NTHREADS, 1) void lstm_persistent(
    const int* __restrict__ tokens, const int* __restrict__ lengths,
    const float* __restrict__ W_ih, const float* __restrict__ W_hh,
    const float* __restrict__ b_ih, const float* __restrict__ b_hh,
    const float* __restrict__ fc_w, const float* __restrict__ fc_b,
    float* __restrict__ out, ull* hg) {
  const int tid = threadIdx.x;
  const int bid = blockIdx.x;
  // XCD-aware: pair p uses blocks with bid%8 in {2p,2p+1} -> 2 XCDs/pair.
  const int xr = bid & 7;
  const int pair = xr >> 1;
  const int w = ((bid >> 3) << 1) | (xr & 1);  // wg-in-pair 0..15

  __shared__ __align__(16) unsigned short hbufP[16][HIDDEN + 8];  // rows 8-15 stay 0
  __shared__ __align__(16) unsigned short hbufQ[16][HIDDEN + 8];
  __shared__ float gatesbP[GBH][RWG + 5];
  __shared__ float gatesbQ[GBH][RWG + 5];
  __shared__ float xgt[VOCAB][RWG + 5];
  __shared__ int lenAll[BATCH];
  __shared__ int order_[BATCH];
  __shared__ int gIdxP[GBH], gLenP[GBH], gIdxQ[GBH], gLenQ[GBH];

  if (tid < BATCH) lenAll[tid] = lengths[tid];
  __syncthreads();
  if (tid < BATCH) {  // stable argsort(-lengths): rank by count
    const int L = lenAll[tid];
    int r = 0;
    for (int jx = 0; jx < BATCH; ++jx) {
      const int lj = lenAll[jx];
      r += ((lj > L) || (lj == L && jx < tid)) ? 1 : 0;
    }
    order_[r] = tid;
  }
  __syncthreads();
  if (tid < GBH) {  // pair ranks [16p,16p+16): P = even local, Q = odd
    const int rp = pair * 16 + 2 * tid;
    const int op = order_[rp], oq = order_[rp + 1];
    gIdxP[tid] = op; gLenP[tid] = lenAll[op];
    gIdxQ[tid] = oq; gLenQ[tid] = lenAll[oq];
  }
  for (int i = tid; i < 16 * (HIDDEN + 8); i += NTHREADS) {
    ((unsigned short*)hbufP)[i] = 0;
    ((unsigned short*)hbufQ)[i] = 0;
  }
  for (int i = tid; i < VOCAB * RWG; i += NTHREADS) {
    const int v = i / RWG, rl = i % RWG;
    const int rg = (rl >> 5) * HIDDEN + w * HSL + (rl & 31);
    xgt[v][rl] = W_ih[rg * VOCAB + v] + b_ih[rg] + b_hh[rg];
  }
  __syncthreads();

  const int TP = gLenP[0];  // pair max (sorted desc); TQ <= TP
  const int TQ = gLenQ[0];
  const int lane = tid & 63;
  const int wv = tid >> 6;
  const int m16 = lane & 15;
  const int quad = lane >> 4;

  // B fragments (bf16 W_hh slice) in VGPRs: wave wv owns ntiles {wv, wv+4}.
  s16x8 Bf[2][16];
#pragma unroll
  for (int nti = 0; nti < 2; ++nti) {
    const int nt = wv + 4 * nti;
    const int rl = nt * 16 + m16;
    const int rg = (rl >> 5) * HIDDEN + w * HSL + (rl & 31);
    const float* wr = W_hh + (size_t)rg * HIDDEN;
#pragma unroll
    for (int kt = 0; kt < 16; ++kt) {
      const float* p = wr + kt * 32 + quad * 8;
#pragma unroll
      for (int e = 0; e < 8; ++e) Bf[nti][kt][e] = (short)f2bf(p[e]);
    }
  }

  // cell mapping: thread (cb,j) owns unit j of batch cb (per group)
  const int cb = tid >> 5;  // 0..7
  const int j = tid & 31;   // 0..31
  // consumer poll mapping: (h128, cbq, pp)
  const int h128 = tid >> 7;
  const int cbq = (tid >> 4) & 7;
  const int pp = tid & 15;
  const int myLenP = gLenP[cb], myLenQ = gLenQ[cb];
  const int* tokRowP = tokens + (size_t)gIdxP[cb] * SEQ;
  const int* tokRowQ = tokens + (size_t)gIdxQ[cb] * SEQ;

  ull* const bP0 = hg + (size_t)(2 * pair) * GQW;
  ull* const bP1 = hg + (size_t)(8 + 2 * pair) * GQW;
  ull* const bQ0 = hg + (size_t)(2 * pair + 1) * GQW;
  ull* const bQ1 = hg + (size_t)(8 + 2 * pair + 1) * GQW;

  const unsigned vo0 = (unsigned)(h128 * 8192 + (cbq * 16 + pp) * 8);
  const unsigned vo1 = vo0 + 4096;
  const int sIdx = w * 256 + cb * 32 + j;  // producer dword index

  ull qP[8], qQ[8];
  float cP = 0.f, hP = 0.f, cQ = 0.f, hQ = 0.f;

  for (int t = 0; t < TP; ++t) {
    const unsigned tu = (unsigned)t;

    // ================= phase P =================
    if (t > 0) {
      asm volatile("s_waitcnt vmcnt(1)" ::: "memory");  // 8 prefetch done (store may linger)
      __builtin_amdgcn_sched_barrier(0);
      bool ok;
      TAGOK8(qP, tu, ok);
      if (!ok) {  // stale prefetch -> spin (always-correct fallback)
        const ull* src = ((t & 1) ? bP1 : bP0) + h128 * 1024 + cbq * 16 + pp;
        for (;;) {
#pragma unroll
          for (int r = 0; r < 8; ++r)
            qP[r] = __hip_atomic_load(src + r * 128, __ATOMIC_RELAXED,
                                      __HIP_MEMORY_SCOPE_AGENT);
          TAGOK8(qP, tu, ok);
          if (ok) break;
        }
      }
#pragma unroll
      for (int r = 0; r < 8; ++r) {  // stage: units (2pp,2pp+1) of producer 8h+r
        const unsigned lo = (unsigned)qP[r] & 0xFFFFu;
        const unsigned hi = (unsigned)(qP[r] >> 32) & 0xFFFFu;
        *(unsigned*)&hbufP[cbq][(h128 * 8 + r) * 32 + 2 * pp] = lo | (hi << 16);
      }
    }
    __syncthreads();
    const int tokP = tokRowP[t];
    {  // MFMA P: [8x512]@[512x128] (A rows 8-15 zero)
      f32x4 a0a = {0.f,0.f,0.f,0.f}, a0b = {0.f,0.f,0.f,0.f};
      f32x4 a1a = {0.f,0.f,0.f,0.f}, a1b = {0.f,0.f,0.f,0.f};
#pragma unroll
      for (int kt = 0; kt < 16; kt += 2) {
        const s16x8 A0 = *(const s16x8*)&hbufP[m16][kt * 32 + quad * 8];
        const s16x8 A1 = *(const s16x8*)&hbufP[m16][(kt + 1) * 32 + quad * 8];
        a0a = __builtin_amdgcn_mfma_f32_16x16x32_bf16(A0, Bf[0][kt], a0a, 0, 0, 0);
        a1a = __builtin_amdgcn_mfma_f32_16x16x32_bf16(A0, Bf[1][kt], a1a, 0, 0, 0);
        a0b = __builtin_amdgcn_mfma_f32_16x16x32_bf16(A1, Bf[0][kt + 1], a0b, 0, 0, 0);
        a1b = __builtin_amdgcn_mfma_f32_16x16x32_bf16(A1, Bf[1][kt + 1], a1b, 0, 0, 0);
      }
      const f32x4 ac0 = a0a + a0b, ac1 = a1a + a1b;
      if (quad < 2) {  // rows m=quad*4+v < 8 valid
#pragma unroll
        for (int v = 0; v < 4; ++v) {
          gatesbP[quad * 4 + v][wv * 16 + m16] = ac0[v];
          gatesbP[quad * 4 + v][(wv + 4) * 16 + m16] = ac1[v];
        }
      }
    }
    __syncthreads();
    if (t > 0 && t < TQ) {  // prefetch Q's step-t words; flight hidden under cell P
      const ull* qb = (t & 1) ? bQ1 : bQ0;
      PREFETCH8(qQ, qb);
    }
    {  // cell P + publish
      const float pi = gatesbP[cb][j] + xgt[tokP][j];
      const float pf = gatesbP[cb][32 + j] + xgt[tokP][32 + j];
      const float pg = gatesbP[cb][64 + j] + xgt[tokP][64 + j];
      const float po = gatesbP[cb][96 + j] + xgt[tokP][96 + j];
      if (t < myLenP) {
        const float ii = sigf(pi), ff = sigf(pf), gg = tanh_fast(pg), oo = sigf(po);
        cP = ff * cP + ii * gg;
        hP = oo * tanh_fast(cP);
      }
      if (t + 1 < TP) {
        unsigned* dst = (unsigned*)(((t + 1) & 1) ? bP1 : bP0) + sIdx;
        __hip_atomic_store(dst, ((unsigned)(t + 1) << 16) | (unsigned)f2bf(hP),
                           __ATOMIC_RELAXED, __HIP_MEMORY_SCOPE_AGENT);
      }
    }

    // ================= phase Q =================
    if (t < TQ) {
      if (t > 0) {
        asm volatile("s_waitcnt vmcnt(1)" ::: "memory");
        __builtin_amdgcn_sched_barrier(0);
        bool ok;
        TAGOK8(qQ, tu, ok);
        if (!ok) {
          const ull* src = ((t & 1) ? bQ1 : bQ0) + h128 * 1024 + cbq * 16 + pp;
          for (;;) {
#pragma unroll
            for (int r = 0; r < 8; ++r)
              qQ[r] = __hip_atomic_load(src + r * 128, __ATOMIC_RELAXED,
                                        __HIP_MEMORY_SCOPE_AGENT);
            TAGOK8(qQ, tu, ok);
            if (ok) break;
          }
        }
#pragma unroll
        for (int r = 0; r < 8; ++r) {
          const unsigned lo = (unsigned)qQ[r] & 0xFFFFu;
          const unsigned hi = (unsigned)(qQ[r] >> 32) & 0xFFFFu;
          *(unsigned*)&hbufQ[cbq][(h128 * 8 + r) * 32 + 2 * pp] = lo | (hi << 16);
        }
      }
      __syncthreads();
      const int tokQ = tokRowQ[t];
      {  // MFMA Q
        f32x4 a0a = {0.f,0.f,0.f,0.f}, a0b = {0.f,0.f,0.f,0.f};
        f32x4 a1a = {0.f,0.f,0.f,0.f}, a1b = {0.f,0.f,0.f,0.f};
#pragma unroll
        for (int kt = 0; kt < 16; kt += 2) {
          const s16x8 A0 = *(const s16x8*)&hbufQ[m16][kt * 32 + quad * 8];
          const s16x8 A1 = *(const s16x8*)&hbufQ[m16][(kt + 1) * 32 + quad * 8];
          a0a = __builtin_amdgcn_mfma_f32_16x16x32_bf16(A0, Bf[0][kt], a0a, 0, 0, 0);
          a1a = __builtin_amdgcn_mfma_f32_16x16x32_bf16(A0, Bf[1][kt], a1a, 0, 0, 0);
          a0b = __builtin_amdgcn_mfma_f32_16x16x32_bf16(A1, Bf[0][kt + 1], a0b, 0, 0, 0);
          a1b = __builtin_amdgcn_mfma_f32_16x16x32_bf16(A1, Bf[1][kt + 1], a1b, 0, 0, 0);
        }
        const f32x4 ac0 = a0a + a0b, ac1 = a1a + a1b;
        if (quad < 2) {
#pragma unroll
          for (int v = 0; v < 4; ++v) {
            gatesbQ[quad * 4 + v][wv * 16 + m16] = ac0[v];
            gatesbQ[quad * 4 + v][(wv + 4) * 16 + m16] = ac1[v];
          }
        }
      }
      __syncthreads();
      if (t + 1 < TP) {  // prefetch P's step-(t+1) words; hidden under cell Q
        const ull* qb = ((t + 1) & 1) ? bP1 : bP0;
        PREFETCH8(qP, qb);
      }
      {  // cell Q + publish
        const float pi = gatesbQ[cb][j] + xgt[tokQ][j];
        const float pf = gatesbQ[cb][32 + j] + xgt[tokQ][32 + j];
        const float pg = gatesbQ[cb][64 + j] + xgt[tokQ][64 + j];
        const float po = gatesbQ[cb][96 + j] + xgt[tokQ][96 + j];
        if (t < myLenQ) {
          const float ii = sigf(pi), ff = sigf(pf), gg = tanh_fast(pg), oo = sigf(po);
          cQ = ff * cQ + ii * gg;
          hQ = oo * tanh_fast(cQ);
        }
        if (t + 1 < TQ) {
          unsigned* dst = (unsigned*)(((t + 1) & 1) ? bQ1 : bQ0) + sIdx;
          __hip_atomic_store(dst, ((unsigned)(t + 1) << 16) | (unsigned)f2bf(hQ),
                             __ATOMIC_RELAXED, __HIP_MEMORY_SCOPE_AGENT);
        }
      }
    } else {
      // Q finished: keep prefetching P (tail; vmcnt(1) may leave last load ->
      // occasional spin, bounded by TP-TQ ~ few steps)
      if (t + 1 < TP) {
        const ull* qb = ((t + 1) & 1) ? bP1 : bP0;
        PREFETCH8(qP, qb);
      }
    }
  }

  // out[rank] = h . fc_w + fc_b; rank P = 16*pair+2cb, Q = +1
  {
    float part = hP * fc_w[w * HSL + j];
    part += __shfl_down(part, 16, 32);
    part += __shfl_down(part, 8, 32);
    part += __shfl_down(part, 4, 32);
    part += __shfl_down(part, 2, 32);
    part += __shfl_down(part, 1, 32);
    if (j == 0) {
      if (w == 0) part += fc_b[0];
      atomicAdd(&out[pair * 16 + 2 * cb], part);
    }
  }
  {
    float part = hQ * fc_w[w * HSL + j];
    part += __shfl_down(part, 16, 32);
    part += __shfl_down(part, 8, 32);
    part += __shfl_down(part, 4, 32);
    part += __shfl_down(part, 2, 32);
    part += __shfl_down(part, 1, 32);
    if (j == 0) {
      if (w == 0) part += fc_b[0];
      atomicAdd(&out[pair * 16 + 2 * cb + 1], part);
    }
  }
}

extern "C" void kernel_launch(void* const* d_in, const int* in_sizes, int n_in,
                              void* d_out, int out_size, void* d_ws, size_t ws_size,
                              hipStream_t stream) {
  (void)in_sizes; (void)n_in; (void)out_size; (void)ws_size;
  const int* tokens = (const int*)d_in[0];
  const int* lengths = (const int*)d_in[1];
  const float* W_ih = (const float*)d_in[2];
  const float* W_hh = (const float*)d_in[3];
  const float* b_ih = (const float*)d_in[4];
  const float* b_hh = (const float*)d_in[5];
  const float* fc_w = (const float*)d_in[6];
  const float* fc_b = (const float*)d_in[7];
  float* out = (float*)d_out;
  ull* hglob = (ull*)d_ws;  // 256 KB tagged h double-buffer (8 groups x 2 parity)

  prep_kernel<<<32, 256, 0, stream>>>(hglob, out);
  lstm_persistent<<<64, NTHREADS, 0, stream>>>(tokens, lengths, W_ih, W_hh, b_ih, b_hh,
                                               fc_w, fc_b, out, hglob);
}